// Round 13
// baseline (49.594 us; speedup 1.0000x reference)
//
#include <hip/hip_runtime.h>

// KFIoU loss: per-row 5-float (x,y,w,h,r) pred/target -> smooth-L1 xy loss +
// KF IoU loss. Outputs: [loss.mean, xy_loss.mean, kf_loss.mean, KFIoU*3 (N)].
//
// R1: atomic storm fixed -> partials + reduce kernel.              (80us)
// R2/R4/R5/R10/R11/R12: six structures, all 22.8-24.4us. Loads,
//     stores, compute each individually not the limiter.
// R6-R9: single-kernel fusion abandoned (wbl2 storm / VGPR collapse
//     / memory-model race at source level).
// R13: queue-depth test — 2 quads (8 rows) per thread, 20 straight-
//     line float4 loads (320B in flight/thread, 2x), 2 packed
//     dwordx4 stores. Discriminates latency-bound vs BW-wall:
//     BW-wall => unchanged => ROOFLINE next round.

#define BLOCK 256

__device__ __forceinline__ void cov_terms(float w, float h, float r,
                                          float& s11, float& s12, float& s22,
                                          float& V) {
    w = fminf(fmaxf(w, 1e-7f), 1e7f);
    h = fminf(fmaxf(h, 1e-7f), 1e7f);
    const float sw = 0.25f * w * w;   // (0.5*w)^2
    const float sh = 0.25f * h * h;
    const float htr = 0.5f * (sw + sh);
    const float hdf = 0.5f * (sw - sh);
    // s11 = htr + cos(2r)*hdf ; s22 = htr - cos(2r)*hdf ; s12 = sin(2r)*hdf
    // hw trig computes sin(2*pi*x); 2r -> x = r/pi, |x|<=1.3: in range.
    const float x = r * 0.3183098861837907f;
    const float s2 = __builtin_amdgcn_sinf(x);
    const float c2 = __builtin_amdgcn_cosf(x);
    s11 = fmaf(c2, hdf, htr);
    s22 = fmaf(-c2, hdf, htr);
    s12 = s2 * hdf;
    V = w * h;
}

__device__ __forceinline__ float kf_row(const float* P, const float* T,
                                        float& xyl, float& kfl) {
    const float dx = fabsf(P[0] - T[0]);
    const float dy = fabsf(P[1] - T[1]);
    const float lx = dx < 1.0f ? 0.5f * dx * dx : dx - 0.5f;
    const float ly = dy < 1.0f ? 0.5f * dy * dy : dy - 0.5f;
    xyl = lx + ly;

    float ap, bp, dp, Vp, at, bt, dt, Vt;
    cov_terms(P[2], P[3], P[4], ap, bp, dp, Vp);
    cov_terms(T[2], T[3], T[4], at, bt, dt, Vt);

    // Sigma = Sp(Sp+St)^-1 St => detS = detSp*detSt/detSum, detSp=(Vp/4)^2
    // => Vb = 4*sqrt(detS) = 0.25*Vp*Vt*rsqrt(detSum)
    const float A = ap + at, B = bp + bt, D = dp + dt;
    const float detSum = fmaf(A, D, -B * B);
    const float Vb = (detSum > 0.0f)
                         ? 0.25f * Vp * Vt * __builtin_amdgcn_rsqf(detSum)
                         : 0.0f;
    const float kfiou = Vb * __builtin_amdgcn_rcpf(Vp + Vt - Vb + 1e-6f);
    kfl = 1.0f - kfiou;
    return 3.0f * kfiou;
}

__global__ __launch_bounds__(BLOCK) void kf_main(
    const float4* __restrict__ pred4, const float4* __restrict__ tgt4,
    float* __restrict__ out, float* __restrict__ partials, int n)
{
    const int n8 = n >> 3;                       // row-octets
    const int t  = blockIdx.x * BLOCK + threadIdx.x;
    float sl = 0.f, sx = 0.f, sk = 0.f;

    if (t < n8) {
        // straight-line: 20 independent float4 loads issued before any use
        float P[40], T[40];
        const float4* p4 = pred4 + 10 * (size_t)t;
        const float4* t4 = tgt4  + 10 * (size_t)t;
#pragma unroll
        for (int j = 0; j < 10; ++j) reinterpret_cast<float4*>(P)[j] = p4[j];
#pragma unroll
        for (int j = 0; j < 10; ++j) reinterpret_cast<float4*>(T)[j] = t4[j];

        float vals[8];
#pragma unroll
        for (int k = 0; k < 8; ++k) {
            float xyl, kfl;
            vals[k] = kf_row(P + 5 * k, T + 5 * k, xyl, kfl);
            sl += fmaxf(xyl + kfl, 0.f);
            sx += xyl;
            sk += kfl;
        }
        // two dwordx4 stores per thread (4B-aligned OK)
        __builtin_memcpy(&out[3 + 8 * (size_t)t],     vals,     16);
        __builtin_memcpy(&out[3 + 8 * (size_t)t + 4], vals + 4, 16);
    }
    // leftover rows (n % 8) — dead for N=2M, kept for generality
    const int ri = (n8 << 3) + t;
    if (ri < n) {
        const float* p = (const float*)pred4 + 5 * (size_t)ri;
        const float* q = (const float*)tgt4  + 5 * (size_t)ri;
        float P[5], T[5];
#pragma unroll
        for (int j = 0; j < 5; ++j) { P[j] = p[j]; T[j] = q[j]; }
        float xyl, kfl;
        const float k3 = kf_row(P, T, xyl, kfl);
        out[3 + (size_t)ri] = k3;
        sl += fmaxf(xyl + kfl, 0.f);
        sx += xyl;
        sk += kfl;
    }

    // wave64 tree reduce (fp32)
#pragma unroll
    for (int off = 32; off > 0; off >>= 1) {
        sl += __shfl_down(sl, off);
        sx += __shfl_down(sx, off);
        sk += __shfl_down(sk, off);
    }
    __shared__ float smem[3][4];
    const int lane = threadIdx.x & 63;
    const int wave = threadIdx.x >> 6;
    if (lane == 0) {
        smem[0][wave] = sl; smem[1][wave] = sx; smem[2][wave] = sk;
    }
    __syncthreads();
    if (threadIdx.x == 0) {
        float a = 0, b = 0, c = 0;
#pragma unroll
        for (int w = 0; w < 4; ++w) { a += smem[0][w]; b += smem[1][w]; c += smem[2][w]; }
        const int np = gridDim.x;                // plain stores; next dispatch
        partials[blockIdx.x]          = a;       // sees them (stream ordering)
        partials[np + blockIdx.x]     = b;
        partials[2 * np + blockIdx.x] = c;
    }
}

__global__ __launch_bounds__(1024) void kf_reduce(
    const float* __restrict__ partials, float* __restrict__ out,
    int npart, double invn)
{
    double a = 0, b = 0, c = 0;
    for (int i = threadIdx.x; i < npart; i += 1024) {
        a += (double)partials[i];
        b += (double)partials[npart + i];
        c += (double)partials[2 * npart + i];
    }
#pragma unroll
    for (int off = 32; off > 0; off >>= 1) {
        a += __shfl_down(a, off);
        b += __shfl_down(b, off);
        c += __shfl_down(c, off);
    }
    __shared__ double smem[3][16];
    const int lane = threadIdx.x & 63;
    const int wave = threadIdx.x >> 6;
    if (lane == 0) {
        smem[0][wave] = a; smem[1][wave] = b; smem[2][wave] = c;
    }
    __syncthreads();
    if (threadIdx.x == 0) {
        double ra = 0, rb = 0, rc = 0;
#pragma unroll
        for (int w = 0; w < 16; ++w) { ra += smem[0][w]; rb += smem[1][w]; rc += smem[2][w]; }
        out[0] = (float)(ra * invn);
        out[1] = (float)(rb * invn);
        out[2] = (float)(rc * invn);
    }
}

extern "C" void kernel_launch(void* const* d_in, const int* in_sizes, int n_in,
                              void* d_out, int out_size, void* d_ws, size_t ws_size,
                              hipStream_t stream) {
    const float4* pred4 = (const float4*)d_in[0];
    const float4* tgt4  = (const float4*)d_in[1];
    float* out = (float*)d_out;
    float* partials = (float*)d_ws;

    const int n  = in_sizes[0] / 5;                // 2,000,000
    const int n8 = n >> 3;                         // 250,000
    const int nblocks = (n8 + BLOCK - 1) / BLOCK;  // 977

    kf_main<<<nblocks, BLOCK, 0, stream>>>(pred4, tgt4, out, partials, n);
    kf_reduce<<<1, 1024, 0, stream>>>(partials, out, nblocks, 1.0 / (double)n);
}